// Round 14
// baseline (853.239 us; speedup 1.0000x reference)
//
#include <hip/hip_runtime.h>

#define N_NODES 100000
#define PADM    100096   // 782 * 128
#define N_EDGES 1000000
#define N_GRAPHS 2000
#define D 64

typedef __bf16    bf16x8 __attribute__((ext_vector_type(8)));
typedef __bf16    bf16x4 __attribute__((ext_vector_type(4)));
typedef float     f32x4  __attribute__((ext_vector_type(4)));

// Fragment-packed element offset (see R10): one MFMA fragment = 1024 contiguous B.
__device__ __forceinline__ size_t apack(int row, int col, int fpr) {
  int frag = (row >> 4) * fpr + (col >> 5);
  int lane = (((col & 31) >> 3) << 4) | (row & 15);
  return (size_t)frag * 512 + lane * 8 + (col & 7);
}

// ===================== CSR build (once, reused for 3 layers) =====================
__global__ __launch_bounds__(256) void deg_hist_kernel(
    const int* __restrict__ ei, int* __restrict__ deg)
{
  int i = blockIdx.x * blockDim.x + threadIdx.x;
  if (i < N_EDGES) atomicAdd(&deg[ei[N_EDGES + i]], 1);
}

__global__ __launch_bounds__(256) void scan1_kernel(
    const int* __restrict__ deg, int* __restrict__ incl, int* __restrict__ bsum)
{
  __shared__ int sh[256];
  int t = threadIdx.x;
  int base = blockIdx.x * 2048 + t * 8;
  int v[8];
  int run = 0;
#pragma unroll
  for (int j = 0; j < 8; ++j) {
    int idx = base + j;
    int xv = (idx < N_NODES) ? deg[idx] : 0;
    run += xv;
    v[j] = run;
  }
  sh[t] = run;
  __syncthreads();
  for (int off = 1; off < 256; off <<= 1) {
    int a = (t >= off) ? sh[t - off] : 0;
    __syncthreads();
    sh[t] += a;
    __syncthreads();
  }
  int prev = (t > 0) ? sh[t - 1] : 0;
#pragma unroll
  for (int j = 0; j < 8; ++j) {
    int idx = base + j;
    if (idx < N_NODES) incl[idx] = v[j] + prev;
  }
  if (t == 255) bsum[blockIdx.x] = sh[255];
}

__global__ void scan2_kernel(int* __restrict__ bsum, int nb)
{
  if (blockIdx.x == 0 && threadIdx.x == 0) {
    int run = 0;
    for (int i = 0; i < nb; ++i) { int xv = bsum[i]; bsum[i] = run; run += xv; }
  }
}

__global__ __launch_bounds__(256) void scan3_kernel(
    const int* __restrict__ incl, const int* __restrict__ bsum,
    const int* __restrict__ deg, int* __restrict__ row_ptr, int* __restrict__ cursor)
{
  int i = blockIdx.x * blockDim.x + threadIdx.x;
  if (i < N_NODES) {
    int val = incl[i] + bsum[i >> 11];
    row_ptr[i + 1] = val;
    cursor[i] = val - deg[i];
    if (i == 0) row_ptr[0] = 0;
  }
}

__global__ __launch_bounds__(256) void fill_csr_kernel(
    const int* __restrict__ ei, int* __restrict__ cursor, int* __restrict__ srcs)
{
  int i = blockIdx.x * blockDim.x + threadIdx.x;
  if (i < N_EDGES) {
    int s = ei[i];
    int d = ei[N_EDGES + i];
    int pos = atomicAdd(&cursor[d], 1);
    srcs[pos] = s;
  }
}

// ---- split f32 x into PACKED bf16 hi/lo planes (K=64, FPR=2) ----
__global__ __launch_bounds__(256) void split_x_kernel(
    const float* __restrict__ x, __bf16* __restrict__ xhi, __bf16* __restrict__ xlo)
{
  int idx = blockIdx.x * blockDim.x + threadIdx.x;
  if (idx >= N_NODES * 16) return;
  int v = idx >> 4, c4 = (idx & 15) << 2;
  float4 xv = *(const float4*)(x + (size_t)v * D + c4);
  float p[4] = {xv.x, xv.y, xv.z, xv.w};
  bf16x4 vh, vl;
#pragma unroll
  for (int j = 0; j < 4; ++j) {
    __bf16 h = (__bf16)p[j];
    vh[j] = h;
    vl[j] = (__bf16)(p[j] - (float)h);
  }
  size_t o = apack(v, c4, 2);
  *(bf16x4*)(xhi + o) = vh;
  *(bf16x4*)(xlo + o) = vl;
}

// ---- weights: split to PACKED bf16 hi/lo B-operand layouts ----
__global__ __launch_bounds__(256) void wconv_kernel(
    const float* __restrict__ W0, const float* __restrict__ W1,
    const float* __restrict__ convW,
    __bf16* __restrict__ w0hi, __bf16* __restrict__ w0lo,
    __bf16* __restrict__ w1hi, __bf16* __restrict__ w1lo,
    __bf16* __restrict__ cwhi, __bf16* __restrict__ cwlo)
{
  int i = blockIdx.x * 256 + threadIdx.x;
  if (i < 65536) {               // W0 [k=256][n=256]
    int k = i >> 8, n = i & 255;
    float v = W0[i];
    __bf16 h = (__bf16)v;
    size_t o = apack(n, k, 8);
    w0hi[o] = h;
    w0lo[o] = (__bf16)(v - (float)h);
  }
  if (i < 32768) {               // W1 [k=256][n=128]
    int k = i >> 7, n = i & 127;
    float v = W1[i];
    __bf16 h = (__bf16)v;
    size_t o = apack(n, k, 8);
    w1hi[o] = h;
    w1lo[o] = (__bf16)(v - (float)h);
  }
  if (i < 12288) {               // convW [3][k=64][n=64]
    int l = i >> 12, rem = i & 4095;
    int k = rem >> 6, n = rem & 63;
    float v = convW[i];
    __bf16 h = (__bf16)v;
    size_t o = (size_t)l * 4096 + apack(n, k, 2);
    cwhi[o] = h;
    cwlo[o] = (__bf16)(v - (float)h);
  }
}

// ---- ygemm: ysl = A @ W  (MFMA 4-term bf16 split, f32 out, no bias) ----
// Output layout: ysl[8][PADM][8] — 8-column slices, each slice contiguous
// (3.2 MB, fits one XCD's 4 MB L2 for the slice-pinned gather in agg_bn).
__global__ __launch_bounds__(256) void ygemm_kernel(
    const __bf16* __restrict__ Ahi, const __bf16* __restrict__ Alo,
    int fpr, int fbase,
    const __bf16* __restrict__ cwh, const __bf16* __restrict__ cwl,
    float* __restrict__ ysl)
{
  int t = threadIdx.x;
  int wid = t >> 6, lane = t & 63;
  int bm0 = blockIdx.x * 64 + wid * 16;
  int rowtile = bm0 >> 4;
  int l15 = lane & 15;
  f32x4 acc[4];
#pragma unroll
  for (int j = 0; j < 4; ++j) acc[j] = (f32x4){0.f, 0.f, 0.f, 0.f};

#pragma unroll
  for (int kc = 0; kc < 2; ++kc) {
    bf16x8 ah, al, bh[4], bl[4];
    {
      size_t off = (size_t)(rowtile * fpr + fbase + kc) * 512 + lane * 8;
      ah = *(const bf16x8*)(Ahi + off);
      al = *(const bf16x8*)(Alo + off);
    }
#pragma unroll
    for (int ct = 0; ct < 4; ++ct) {
      size_t off = (size_t)(ct * 2 + kc) * 512 + lane * 8;
      bh[ct] = *(const bf16x8*)(cwh + off);
      bl[ct] = *(const bf16x8*)(cwl + off);
    }
#pragma unroll
    for (int ct = 0; ct < 4; ++ct) {
      acc[ct] = __builtin_amdgcn_mfma_f32_16x16x32_bf16(ah, bh[ct], acc[ct], 0, 0, 0);
      acc[ct] = __builtin_amdgcn_mfma_f32_16x16x32_bf16(al, bh[ct], acc[ct], 0, 0, 0);
      acc[ct] = __builtin_amdgcn_mfma_f32_16x16x32_bf16(ah, bl[ct], acc[ct], 0, 0, 0);
      acc[ct] = __builtin_amdgcn_mfma_f32_16x16x32_bf16(al, bl[ct], acc[ct], 0, 0, 0);
    }
  }
  int rbase = (lane >> 4) * 4;
#pragma unroll
  for (int ct = 0; ct < 4; ++ct)
#pragma unroll
    for (int r = 0; r < 4; ++r) {
      int col = 16 * ct + l15;
      int node = bm0 + rbase + r;
      ysl[(size_t)(col >> 3) * (PADM * 8) + (size_t)node * 8 + (col & 7)] = acc[ct][r];
    }
}

// ---- agg_bn, column-sliced + XCD-pinned ----
// slice = blockIdx % 8 -> with round-robin block->XCD dispatch, each XCD
// gathers only from its 3.2 MB ysl slice (L2-resident after first touch).
// Wave: lane = e8*8+c processes 8 edges x 8 cols per load; shfl_xor reduce.
template <int POOL>
__global__ __launch_bounds__(256) void agg_bn_kernel(
    const float* __restrict__ ysl,
    const int* __restrict__ row_ptr, const int* __restrict__ srcs,
    const float* __restrict__ bias,
    const float* __restrict__ gamma, const float* __restrict__ beta,
    const float* __restrict__ mean, const float* __restrict__ var,
    const float* __restrict__ epsp,
    __bf16* __restrict__ ohi, __bf16* __restrict__ olo, int oc0,
    float* __restrict__ hpool, const int* __restrict__ batch)
{
  int slice = blockIdx.x & 7;
  int nb = blockIdx.x >> 3;
  int w = threadIdx.x >> 6;
  int lane = threadIdx.x & 63;
  int e8 = lane >> 3, c = lane & 7;
  const float* ys = ysl + (size_t)slice * (PADM * 8);
  int cb = slice * 8 + c;
  float onepe = 1.0f + epsp[0];
  float sc = gamma[cb] * rsqrtf(var[cb] + 1e-5f);
  float bb = bias[cb], mm = mean[cb], tt = beta[cb];
  int n0 = nb * 64 + w * 16;
#pragma unroll 1
  for (int i = 0; i < 16; ++i) {
    int n = n0 + i;
    if (n >= N_NODES) break;
    int beg = row_ptr[n], end = row_ptr[n + 1];
    float s = 0.f;
    for (int e0 = beg; e0 < end; e0 += 8) {
      int e = e0 + e8;
      float v = 0.f;
      if (e < end) v = ys[(size_t)srcs[e] * 8 + c];
      s += v;
    }
    s += __shfl_xor(s, 8);
    s += __shfl_xor(s, 16);
    s += __shfl_xor(s, 32);
    float own = ys[(size_t)n * 8 + c];
    float z = (onepe * own + s + bb - mm) * sc + tt;
    z = (z > 0.f) ? z : 0.01f * z;
    z = (z > 0.f) ? z : 0.01f * z;
    if (e8 == 0) {
      __bf16 h = (__bf16)z;
      size_t o = apack(n, oc0 + cb, 8);
      ohi[o] = h;
      olo[o] = (__bf16)(z - (float)h);
      if (POOL)
        unsafeAtomicAdd(&hpool[(size_t)batch[n] * D + cb], z);
    }
  }
}

// ---- pool rows -> packed concat cols 192..255 (hi/lo bf16) ----
__global__ __launch_bounds__(256) void pool_expand_kernel(
    const float* __restrict__ hpool, const int* __restrict__ batch,
    __bf16* __restrict__ ohi, __bf16* __restrict__ olo)
{
  int idx = blockIdx.x * blockDim.x + threadIdx.x;
  int v = idx >> 4, c4 = (idx & 15) << 2;
  if (v >= N_NODES) return;
  int g = batch[v];
  float4 pv = *(const float4*)(hpool + (size_t)g * D + c4);
  float p[4] = {pv.x, pv.y, pv.z, pv.w};
  bf16x4 vh, vl;
#pragma unroll
  for (int j = 0; j < 4; ++j) {
    __bf16 h = (__bf16)p[j];
    vh[j] = h;
    vl[j] = (__bf16)(p[j] - (float)h);
  }
  size_t o = apack(v, 192 + c4, 8);
  *(bf16x4*)(ohi + o) = vh;
  *(bf16x4*)(olo + o) = vl;
}

// ==== fused classifier (R10 version) ====
// 64 rows/block, 256 thr = 4 waves (2 row-groups x 2 col-groups).
// Packed 1-KB fragment loads; N split into two 128-col halves; ha-half staged
// in LDS (bf16 hi/lo, XOR-swizzled); h2 accumulator persists in registers.
// 3-term bf16 splits. R11: reg double-buffering REGRESSED (occupancy loss).
__global__ __launch_bounds__(256) void clf_fused_kernel(
    const __bf16* __restrict__ Ahi, const __bf16* __restrict__ Alo,
    const __bf16* __restrict__ w0h, const __bf16* __restrict__ w0l,
    const float* __restrict__ b0,
    const __bf16* __restrict__ w1h, const __bf16* __restrict__ w1l,
    const float* __restrict__ b1,
    const float* __restrict__ Wf, const float* __restrict__ fbias,
    float* __restrict__ out)
{
  __shared__ __bf16 HaS[64 * 128];
  __shared__ __bf16 LaS[64 * 128];
  int t = threadIdx.x;
  int w = t >> 6, lane = t & 63;
  int wr = w >> 1, wc = w & 1;
  int l15 = lane & 15, g = lane >> 4, lk = g * 8;
  int bm0 = blockIdx.x * 64;
  int rtile0 = (bm0 >> 4) + 2 * wr;

  f32x4 acc2[2][4];
#pragma unroll
  for (int i = 0; i < 2; ++i)
#pragma unroll
    for (int j = 0; j < 4; ++j) acc2[i][j] = (f32x4){0.f, 0.f, 0.f, 0.f};

  for (int h = 0; h < 2; ++h) {
    // ---- Phase A (half h): ha[:, 128h..128h+128) ----
    f32x4 acc[2][4];
#pragma unroll
    for (int i = 0; i < 2; ++i)
#pragma unroll
      for (int j = 0; j < 4; ++j) acc[i][j] = (f32x4){0.f, 0.f, 0.f, 0.f};

    int ntile0 = 8 * h + 4 * wc;
    for (int ks = 0; ks < 8; ++ks) {
      bf16x8 ah[2], al[2], bh[4], bl[4];
#pragma unroll
      for (int rt = 0; rt < 2; ++rt) {
        size_t off = (size_t)((rtile0 + rt) * 8 + ks) * 512 + lane * 8;
        ah[rt] = *(const bf16x8*)(Ahi + off);
        al[rt] = *(const bf16x8*)(Alo + off);
      }
#pragma unroll
      for (int ct = 0; ct < 4; ++ct) {
        size_t off = (size_t)((ntile0 + ct) * 8 + ks) * 512 + lane * 8;
        bh[ct] = *(const bf16x8*)(w0h + off);
        bl[ct] = *(const bf16x8*)(w0l + off);
      }
#pragma unroll
      for (int rt = 0; rt < 2; ++rt)
#pragma unroll
        for (int ct = 0; ct < 4; ++ct) {
          acc[rt][ct] = __builtin_amdgcn_mfma_f32_16x16x32_bf16(ah[rt], bh[ct], acc[rt][ct], 0, 0, 0);
          acc[rt][ct] = __builtin_amdgcn_mfma_f32_16x16x32_bf16(al[rt], bh[ct], acc[rt][ct], 0, 0, 0);
          acc[rt][ct] = __builtin_amdgcn_mfma_f32_16x16x32_bf16(ah[rt], bl[ct], acc[rt][ct], 0, 0, 0);
        }
    }
    // epilogue A: bias + leaky, split hi/lo, swizzled LDS store
#pragma unroll
    for (int rt = 0; rt < 2; ++rt)
#pragma unroll
      for (int ct = 0; ct < 4; ++ct) {
        int coll = 64 * wc + 16 * ct + l15;
        float bb = b0[128 * h + coll];
#pragma unroll
        for (int r = 0; r < 4; ++r) {
          int rowl = 32 * wr + 16 * rt + 4 * g + r;
          float z = acc[rt][ct][r] + bb;
          z = (z > 0.f) ? z : 0.01f * z;
          __bf16 hv = (__bf16)z;
          unsigned bo = (unsigned)(rowl * 256 + coll * 2) ^ ((rowl & 7) << 4);
          *(__bf16*)((char*)HaS + bo) = hv;
          *(__bf16*)((char*)LaS + bo) = (__bf16)(z - (float)hv);
        }
      }
    __syncthreads();

    // ---- Phase B (half h): acc2 += ha_half @ W1t[:, 128h..128h+128) ----
    for (int ks = 0; ks < 4; ++ks) {
      int kl = ks * 32;
      bf16x8 ah2[2], al2[2], b2h[4], b2l[4];
#pragma unroll
      for (int rt = 0; rt < 2; ++rt) {
        int rowl = 32 * wr + 16 * rt + l15;
        unsigned bo = (unsigned)(rowl * 256 + (kl + lk) * 2) ^ ((rowl & 7) << 4);
        ah2[rt] = *(const bf16x8*)((char*)HaS + bo);
        al2[rt] = *(const bf16x8*)((char*)LaS + bo);
      }
#pragma unroll
      for (int ct = 0; ct < 4; ++ct) {
        size_t off = (size_t)((4 * wc + ct) * 8 + 4 * h + ks) * 512 + lane * 8;
        b2h[ct] = *(const bf16x8*)(w1h + off);
        b2l[ct] = *(const bf16x8*)(w1l + off);
      }
#pragma unroll
      for (int rt = 0; rt < 2; ++rt)
#pragma unroll
        for (int ct = 0; ct < 4; ++ct) {
          acc2[rt][ct] = __builtin_amdgcn_mfma_f32_16x16x32_bf16(ah2[rt], b2h[ct], acc2[rt][ct], 0, 0, 0);
          acc2[rt][ct] = __builtin_amdgcn_mfma_f32_16x16x32_bf16(al2[rt], b2h[ct], acc2[rt][ct], 0, 0, 0);
          acc2[rt][ct] = __builtin_amdgcn_mfma_f32_16x16x32_bf16(ah2[rt], b2l[ct], acc2[rt][ct], 0, 0, 0);
        }
    }
    __syncthreads();
  }

  // ---- final: bias1 + leaky, dot Wf, 16-lane reduce, cross-wave-col partials ----
  float* partS = (float*)HaS;
#pragma unroll
  for (int rt = 0; rt < 2; ++rt) {
#pragma unroll
    for (int r = 0; r < 4; ++r) {
      int rowl = 32 * wr + 16 * rt + 4 * g + r;
      float p = 0.f;
#pragma unroll
      for (int ct = 0; ct < 4; ++ct) {
        int c = 64 * wc + 16 * ct + l15;
        float z = acc2[rt][ct][r] + b1[c];
        z = (z > 0.f) ? z : 0.01f * z;
        p += z * Wf[c];
      }
      p += __shfl_xor(p, 1);
      p += __shfl_xor(p, 2);
      p += __shfl_xor(p, 4);
      p += __shfl_xor(p, 8);
      if (l15 == 0) partS[wc * 64 + rowl] = p;
    }
  }
  __syncthreads();
  if (t < 64) {
    int gl = bm0 + t;
    if (gl < N_NODES) {
      float z = partS[t] + partS[64 + t] + fbias[0];
      out[gl] = 1.0f / (1.0f + expf(-z));
    }
  }
}

extern "C" void kernel_launch(void* const* d_in, const int* in_sizes, int n_in,
                              void* d_out, int out_size, void* d_ws, size_t ws_size,
                              hipStream_t stream)
{
  const float* x     = (const float*)d_in[0];
  const int*   ei    = (const int*)d_in[1];
  const int*   batch = (const int*)d_in[2];
  const float* convW = (const float*)d_in[3];
  const float* convb = (const float*)d_in[4];
  const float* gam   = (const float*)d_in[5];
  const float* bet   = (const float*)d_in[6];
  const float* mean  = (const float*)d_in[7];
  const float* var   = (const float*)d_in[8];
  const float* eps   = (const float*)d_in[9];
  const float* W0    = (const float*)d_in[10];
  const float* b0    = (const float*)d_in[11];
  const float* W1    = (const float*)d_in[12];
  const float* b1    = (const float*)d_in[13];
  const float* Wf    = (const float*)d_in[14];
  const float* fb    = (const float*)d_in[15];
  float* out = (float*)d_out;

  // ---- workspace layout (float offsets), peak ~160.3 MB (unchanged) ----
  float* ws = (float*)d_ws;
  __bf16* A0hi = (__bf16*)(ws);
  __bf16* A0lo = (__bf16*)(ws + 12812288);
  float*  y    = ws + 25624576;            // ysl[8][PADM][8] slice-blocked
  __bf16* xhi  = (__bf16*)(ws + 32030720);
  __bf16* xlo  = (__bf16*)(ws + 35230720);
  int* deg     = (int*)(ws + 38436864);
  int* incl    = (int*)(ws + 38536864);
  int* row_ptr = (int*)(ws + 38636864);
  int* cursor  = (int*)(ws + 38736896);
  int* srcs    = (int*)(ws + 38836896);
  int* bsum    = (int*)(ws + 39836896);
  float* hpool = ws + 39836960;
  __bf16* w0hi = (__bf16*)(ws + 39964960);
  __bf16* w0lo = (__bf16*)(ws + 39997728);
  __bf16* w1hi = (__bf16*)(ws + 40030496);
  __bf16* w1lo = (__bf16*)(ws + 40046880);
  __bf16* cwhi = (__bf16*)(ws + 40063264);
  __bf16* cwlo = (__bf16*)(ws + 40069408);

  dim3 b256(256);

  wconv_kernel<<<256, b256, 0, stream>>>(W0, W1, convW, w0hi, w0lo, w1hi, w1lo, cwhi, cwlo);

  // ---- CSR build (once) ----
  hipMemsetAsync(deg, 0, (size_t)N_NODES * sizeof(int), stream);
  deg_hist_kernel<<<(N_EDGES + 255) / 256, b256, 0, stream>>>(ei, deg);
  scan1_kernel<<<(N_NODES + 2047) / 2048, b256, 0, stream>>>(deg, incl, bsum);
  scan2_kernel<<<1, 64, 0, stream>>>(bsum, (N_NODES + 2047) / 2048);
  scan3_kernel<<<(N_NODES + 255) / 256, b256, 0, stream>>>(incl, bsum, deg, row_ptr, cursor);
  fill_csr_kernel<<<(N_EDGES + 255) / 256, b256, 0, stream>>>(ei, cursor, srcs);

  hipMemsetAsync(hpool, 0, (size_t)N_GRAPHS * D * sizeof(float), stream);
  split_x_kernel<<<(N_NODES * 16 + 255) / 256, b256, 0, stream>>>(x, xhi, xlo);

  int ygrid = PADM / 64;                        // 1564
  int aggGrid = ((N_NODES + 63) / 64) * 8;      // 1563 node-blocks x 8 slices

  // layer 0: x packed (FPR=2), out cols 0..63
  ygemm_kernel<<<ygrid, b256, 0, stream>>>(xhi, xlo, 2, 0, cwhi, cwlo, y);
  agg_bn_kernel<0><<<aggGrid, b256, 0, stream>>>(
      y, row_ptr, srcs, convb, gam, bet, mean, var, eps, A0hi, A0lo, 0, nullptr, nullptr);
  // layer 1: A0 cols 0..63 (FPR=8, fbase=0), out cols 64..127
  ygemm_kernel<<<ygrid, b256, 0, stream>>>(A0hi, A0lo, 8, 0, cwhi + 4096, cwlo + 4096, y);
  agg_bn_kernel<0><<<aggGrid, b256, 0, stream>>>(
      y, row_ptr, srcs, convb + D, gam + D, bet + D, mean + D, var + D, eps + 1,
      A0hi, A0lo, 64, nullptr, nullptr);
  // layer 2: A0 cols 64..127 (fbase=2), out cols 128..191 + pool
  ygemm_kernel<<<ygrid, b256, 0, stream>>>(A0hi, A0lo, 8, 2, cwhi + 8192, cwlo + 8192, y);
  agg_bn_kernel<1><<<aggGrid, b256, 0, stream>>>(
      y, row_ptr, srcs, convb + 2 * D, gam + 2 * D, bet + 2 * D, mean + 2 * D,
      var + 2 * D, eps + 2, A0hi, A0lo, 128, hpool, batch);

  pool_expand_kernel<<<(N_NODES * 16 + 255) / 256, b256, 0, stream>>>(hpool, batch, A0hi, A0lo);

  // ---- fused classifier: 64 rows/block, 256 threads, packed operand loads ----
  clf_fused_kernel<<<PADM / 64, b256, 0, stream>>>(
      A0hi, A0lo, w0hi, w0lo, b0, w1hi, w1lo, b1, Wf, fb, out);
}

// Round 15
// 437.229 us; speedup vs baseline: 1.9515x; 1.9515x over previous
//
#include <hip/hip_runtime.h>

#define N_NODES 100000
#define PADM    100096   // 782 * 128
#define N_EDGES 1000000
#define N_GRAPHS 2000
#define D 64

typedef __bf16    bf16x8 __attribute__((ext_vector_type(8)));
typedef __bf16    bf16x4 __attribute__((ext_vector_type(4)));
typedef float     f32x4  __attribute__((ext_vector_type(4)));

// Fragment-packed element offset: operand matrices are stored so that one
// MFMA fragment (16 rows x 32 k, the exact lane->elem map of
// mfma_f32_16x16x32_bf16) is 1024 contiguous bytes. A wave's fragment load is
// base + frag*512 + lane*8 -> one contiguous 1 KB coalesced load.
__device__ __forceinline__ size_t apack(int row, int col, int fpr) {
  int frag = (row >> 4) * fpr + (col >> 5);
  int lane = (((col & 31) >> 3) << 4) | (row & 15);
  return (size_t)frag * 512 + lane * 8 + (col & 7);
}

// ===================== CSR build (once, reused for 3 layers) =====================
__global__ __launch_bounds__(256) void deg_hist_kernel(
    const int* __restrict__ ei, int* __restrict__ deg)
{
  int i = blockIdx.x * blockDim.x + threadIdx.x;
  if (i < N_EDGES) atomicAdd(&deg[ei[N_EDGES + i]], 1);
}

__global__ __launch_bounds__(256) void scan1_kernel(
    const int* __restrict__ deg, int* __restrict__ incl, int* __restrict__ bsum)
{
  __shared__ int sh[256];
  int t = threadIdx.x;
  int base = blockIdx.x * 2048 + t * 8;
  int v[8];
  int run = 0;
#pragma unroll
  for (int j = 0; j < 8; ++j) {
    int idx = base + j;
    int xv = (idx < N_NODES) ? deg[idx] : 0;
    run += xv;
    v[j] = run;
  }
  sh[t] = run;
  __syncthreads();
  for (int off = 1; off < 256; off <<= 1) {
    int a = (t >= off) ? sh[t - off] : 0;
    __syncthreads();
    sh[t] += a;
    __syncthreads();
  }
  int prev = (t > 0) ? sh[t - 1] : 0;
#pragma unroll
  for (int j = 0; j < 8; ++j) {
    int idx = base + j;
    if (idx < N_NODES) incl[idx] = v[j] + prev;
  }
  if (t == 255) bsum[blockIdx.x] = sh[255];
}

__global__ void scan2_kernel(int* __restrict__ bsum, int nb)
{
  if (blockIdx.x == 0 && threadIdx.x == 0) {
    int run = 0;
    for (int i = 0; i < nb; ++i) { int xv = bsum[i]; bsum[i] = run; run += xv; }
  }
}

__global__ __launch_bounds__(256) void scan3_kernel(
    const int* __restrict__ incl, const int* __restrict__ bsum,
    const int* __restrict__ deg, int* __restrict__ row_ptr, int* __restrict__ cursor)
{
  int i = blockIdx.x * blockDim.x + threadIdx.x;
  if (i < N_NODES) {
    int val = incl[i] + bsum[i >> 11];
    row_ptr[i + 1] = val;
    cursor[i] = val - deg[i];
    if (i == 0) row_ptr[0] = 0;
  }
}

__global__ __launch_bounds__(256) void fill_csr_kernel(
    const int* __restrict__ ei, int* __restrict__ cursor, int* __restrict__ srcs)
{
  int i = blockIdx.x * blockDim.x + threadIdx.x;
  if (i < N_EDGES) {
    int s = ei[i];
    int d = ei[N_EDGES + i];
    int pos = atomicAdd(&cursor[d], 1);
    srcs[pos] = s;
  }
}

// ---- split f32 x into PACKED bf16 hi/lo planes (K=64, FPR=2) ----
__global__ __launch_bounds__(256) void split_x_kernel(
    const float* __restrict__ x, __bf16* __restrict__ xhi, __bf16* __restrict__ xlo)
{
  int idx = blockIdx.x * blockDim.x + threadIdx.x;
  if (idx >= N_NODES * 16) return;
  int v = idx >> 4, c4 = (idx & 15) << 2;
  float4 xv = *(const float4*)(x + (size_t)v * D + c4);
  float p[4] = {xv.x, xv.y, xv.z, xv.w};
  bf16x4 vh, vl;
#pragma unroll
  for (int j = 0; j < 4; ++j) {
    __bf16 h = (__bf16)p[j];
    vh[j] = h;
    vl[j] = (__bf16)(p[j] - (float)h);
  }
  size_t o = apack(v, c4, 2);   // 4 consecutive cols share frag+lane -> contiguous
  *(bf16x4*)(xhi + o) = vh;
  *(bf16x4*)(xlo + o) = vl;
}

// ---- weights: split to PACKED bf16 hi/lo B-operand layouts ----
__global__ __launch_bounds__(256) void wconv_kernel(
    const float* __restrict__ W0, const float* __restrict__ W1,
    const float* __restrict__ convW,
    __bf16* __restrict__ w0hi, __bf16* __restrict__ w0lo,
    __bf16* __restrict__ w1hi, __bf16* __restrict__ w1lo,
    __bf16* __restrict__ cwhi, __bf16* __restrict__ cwlo)
{
  int i = blockIdx.x * 256 + threadIdx.x;
  if (i < 65536) {               // W0 [k=256][n=256], K=256 -> FPR=8 on n-tiles
    int k = i >> 8, n = i & 255;
    float v = W0[i];
    __bf16 h = (__bf16)v;
    size_t o = apack(n, k, 8);   // B operand: "row" = n, "col" = k
    w0hi[o] = h;
    w0lo[o] = (__bf16)(v - (float)h);
  }
  if (i < 32768) {               // W1 [k=256][n=128]
    int k = i >> 7, n = i & 127;
    float v = W1[i];
    __bf16 h = (__bf16)v;
    size_t o = apack(n, k, 8);
    w1hi[o] = h;
    w1lo[o] = (__bf16)(v - (float)h);
  }
  if (i < 12288) {               // convW [3][k=64][n=64], K=64 -> FPR=2
    int l = i >> 12, rem = i & 4095;
    int k = rem >> 6, n = rem & 63;
    float v = convW[i];
    __bf16 h = (__bf16)v;
    size_t o = (size_t)l * 4096 + apack(n, k, 2);
    cwhi[o] = h;
    cwlo[o] = (__bf16)(v - (float)h);
  }
}

// ---- ygemm: y = A @ W  (MFMA 4-term bf16 split, f32 out, no bias) ----
// A packed with given FPR; fbase = starting k-chunk (col offset / 32).
__global__ __launch_bounds__(256) void ygemm_kernel(
    const __bf16* __restrict__ Ahi, const __bf16* __restrict__ Alo,
    int fpr, int fbase,
    const __bf16* __restrict__ cwh, const __bf16* __restrict__ cwl,
    float* __restrict__ y)
{
  int t = threadIdx.x;
  int wid = t >> 6, lane = t & 63;
  int bm0 = blockIdx.x * 64 + wid * 16;
  int rowtile = bm0 >> 4;
  int l15 = lane & 15;
  f32x4 acc[4];
#pragma unroll
  for (int j = 0; j < 4; ++j) acc[j] = (f32x4){0.f, 0.f, 0.f, 0.f};

#pragma unroll
  for (int kc = 0; kc < 2; ++kc) {
    bf16x8 ah, al, bh[4], bl[4];
    {
      size_t off = (size_t)(rowtile * fpr + fbase + kc) * 512 + lane * 8;
      ah = *(const bf16x8*)(Ahi + off);
      al = *(const bf16x8*)(Alo + off);
    }
#pragma unroll
    for (int ct = 0; ct < 4; ++ct) {
      size_t off = (size_t)(ct * 2 + kc) * 512 + lane * 8;
      bh[ct] = *(const bf16x8*)(cwh + off);
      bl[ct] = *(const bf16x8*)(cwl + off);
    }
#pragma unroll
    for (int ct = 0; ct < 4; ++ct) {
      acc[ct] = __builtin_amdgcn_mfma_f32_16x16x32_bf16(ah, bh[ct], acc[ct], 0, 0, 0);
      acc[ct] = __builtin_amdgcn_mfma_f32_16x16x32_bf16(al, bh[ct], acc[ct], 0, 0, 0);
      acc[ct] = __builtin_amdgcn_mfma_f32_16x16x32_bf16(ah, bl[ct], acc[ct], 0, 0, 0);
      acc[ct] = __builtin_amdgcn_mfma_f32_16x16x32_bf16(al, bl[ct], acc[ct], 0, 0, 0);
    }
  }
  int rbase = (lane >> 4) * 4;
#pragma unroll
  for (int ct = 0; ct < 4; ++ct)
#pragma unroll
    for (int r = 0; r < 4; ++r)
      y[(size_t)(bm0 + rbase + r) * D + 16 * ct + l15] = acc[ct][r];
}

// ---- fused: pre = (1+eps)*y_i + sum_j y_j + b; BN; leaky^2; packed-store; pool ----
// One node per wave; each edge gather = one fully-coalesced 256 B wave load.
// (R12's 4-node/wave, R13's row-sort, R14's column-slicing all regressed.)
template <int POOL>
__global__ __launch_bounds__(256) void agg_bn_kernel(
    const float* __restrict__ y,
    const int* __restrict__ row_ptr, const int* __restrict__ srcs,
    const float* __restrict__ bias,
    const float* __restrict__ gamma, const float* __restrict__ beta,
    const float* __restrict__ mean, const float* __restrict__ var,
    const float* __restrict__ epsp,
    __bf16* __restrict__ ohi, __bf16* __restrict__ olo, int oc0,
    float* __restrict__ hpool, const int* __restrict__ batch)
{
  int wid = (blockIdx.x * blockDim.x + threadIdx.x) >> 6;
  int lane = threadIdx.x & 63;
  if (wid >= N_NODES) return;
  float onepe = 1.0f + epsp[0];
  int beg = row_ptr[wid];
  int end = row_ptr[wid + 1];
  float s = onepe * y[(size_t)wid * D + lane];
  int e = beg;
  for (; e + 8 <= end; e += 8) {
    int i0 = srcs[e], i1 = srcs[e + 1], i2 = srcs[e + 2], i3 = srcs[e + 3];
    int i4 = srcs[e + 4], i5 = srcs[e + 5], i6 = srcs[e + 6], i7 = srcs[e + 7];
    float a0 = y[(size_t)i0 * D + lane];
    float a1 = y[(size_t)i1 * D + lane];
    float a2 = y[(size_t)i2 * D + lane];
    float a3 = y[(size_t)i3 * D + lane];
    float a4 = y[(size_t)i4 * D + lane];
    float a5 = y[(size_t)i5 * D + lane];
    float a6 = y[(size_t)i6 * D + lane];
    float a7 = y[(size_t)i7 * D + lane];
    s += ((a0 + a1) + (a2 + a3)) + ((a4 + a5) + (a6 + a7));
  }
  for (; e + 4 <= end; e += 4) {
    int i0 = srcs[e], i1 = srcs[e + 1], i2 = srcs[e + 2], i3 = srcs[e + 3];
    float a0 = y[(size_t)i0 * D + lane];
    float a1 = y[(size_t)i1 * D + lane];
    float a2 = y[(size_t)i2 * D + lane];
    float a3 = y[(size_t)i3 * D + lane];
    s += (a0 + a1) + (a2 + a3);
  }
  for (; e < end; ++e) s += y[(size_t)srcs[e] * D + lane];

  float sc = gamma[lane] * rsqrtf(var[lane] + 1e-5f);
  float z = (s + bias[lane] - mean[lane]) * sc + beta[lane];
  z = (z > 0.f) ? z : 0.01f * z;
  z = (z > 0.f) ? z : 0.01f * z;
  __bf16 h = (__bf16)z;
  size_t o = apack(wid, oc0 + lane, 8);
  ohi[o] = h;
  olo[o] = (__bf16)(z - (float)h);
  if (POOL) {
    int g = batch[wid];
    unsafeAtomicAdd(&hpool[(size_t)g * D + lane], z);
  }
}

// ---- pool rows -> packed concat cols 192..255 (hi/lo bf16) ----
__global__ __launch_bounds__(256) void pool_expand_kernel(
    const float* __restrict__ hpool, const int* __restrict__ batch,
    __bf16* __restrict__ ohi, __bf16* __restrict__ olo)
{
  int idx = blockIdx.x * blockDim.x + threadIdx.x;
  int v = idx >> 4, c4 = (idx & 15) << 2;
  if (v >= N_NODES) return;
  int g = batch[v];
  float4 pv = *(const float4*)(hpool + (size_t)g * D + c4);
  float p[4] = {pv.x, pv.y, pv.z, pv.w};
  bf16x4 vh, vl;
#pragma unroll
  for (int j = 0; j < 4; ++j) {
    __bf16 h = (__bf16)p[j];
    vh[j] = h;
    vl[j] = (__bf16)(p[j] - (float)h);
  }
  size_t o = apack(v, 192 + c4, 8);
  *(bf16x4*)(ohi + o) = vh;
  *(bf16x4*)(olo + o) = vl;
}

// ==== fused classifier: out = sigmoid(leaky(leaky(A0@W0+b0)@W1+b1)·Wf + fb) ====
// 64 rows/block, 256 thr = 4 waves (2 row-groups x 2 col-groups).
// All global operand loads are packed-fragment (1 contiguous KB per wave-load).
// N split into two 128-col halves; ha-half staged in LDS (bf16 hi/lo,
// XOR-swizzled); h2 accumulator persists in registers. 3-term bf16 splits.
// R11 lesson: reg double-buffering (VGPR 120->156, occupancy 17->10%)
// REGRESSED 103->127 us — wave-TLP already hides the L2 latency here.
__global__ __launch_bounds__(256) void clf_fused_kernel(
    const __bf16* __restrict__ Ahi, const __bf16* __restrict__ Alo,
    const __bf16* __restrict__ w0h, const __bf16* __restrict__ w0l,
    const float* __restrict__ b0,
    const __bf16* __restrict__ w1h, const __bf16* __restrict__ w1l,
    const float* __restrict__ b1,
    const float* __restrict__ Wf, const float* __restrict__ fbias,
    float* __restrict__ out)
{
  __shared__ __bf16 HaS[64 * 128];
  __shared__ __bf16 LaS[64 * 128];
  int t = threadIdx.x;
  int w = t >> 6, lane = t & 63;
  int wr = w >> 1, wc = w & 1;
  int l15 = lane & 15, g = lane >> 4, lk = g * 8;
  int bm0 = blockIdx.x * 64;
  int rtile0 = (bm0 >> 4) + 2 * wr;      // wave's first row-tile index

  f32x4 acc2[2][4];
#pragma unroll
  for (int i = 0; i < 2; ++i)
#pragma unroll
    for (int j = 0; j < 4; ++j) acc2[i][j] = (f32x4){0.f, 0.f, 0.f, 0.f};

  for (int h = 0; h < 2; ++h) {
    // ---- Phase A (half h): ha[:, 128h..128h+128) ----
    f32x4 acc[2][4];
#pragma unroll
    for (int i = 0; i < 2; ++i)
#pragma unroll
      for (int j = 0; j < 4; ++j) acc[i][j] = (f32x4){0.f, 0.f, 0.f, 0.f};

    int ntile0 = 8 * h + 4 * wc;         // wave's first n-tile of W0
    for (int ks = 0; ks < 8; ++ks) {
      bf16x8 ah[2], al[2], bh[4], bl[4];
#pragma unroll
      for (int rt = 0; rt < 2; ++rt) {
        size_t off = (size_t)((rtile0 + rt) * 8 + ks) * 512 + lane * 8;
        ah[rt] = *(const bf16x8*)(Ahi + off);
        al[rt] = *(const bf16x8*)(Alo + off);
      }
#pragma unroll
      for (int ct = 0; ct < 4; ++ct) {
        size_t off = (size_t)((ntile0 + ct) * 8 + ks) * 512 + lane * 8;
        bh[ct] = *(const bf16x8*)(w0h + off);
        bl[ct] = *(const bf16x8*)(w0l + off);
      }
#pragma unroll
      for (int rt = 0; rt < 2; ++rt)
#pragma unroll
        for (int ct = 0; ct < 4; ++ct) {
          acc[rt][ct] = __builtin_amdgcn_mfma_f32_16x16x32_bf16(ah[rt], bh[ct], acc[rt][ct], 0, 0, 0);
          acc[rt][ct] = __builtin_amdgcn_mfma_f32_16x16x32_bf16(al[rt], bh[ct], acc[rt][ct], 0, 0, 0);
          acc[rt][ct] = __builtin_amdgcn_mfma_f32_16x16x32_bf16(ah[rt], bl[ct], acc[rt][ct], 0, 0, 0);
        }
    }
    // epilogue A: bias + leaky, split hi/lo, swizzled LDS store (local cols 0..127)
#pragma unroll
    for (int rt = 0; rt < 2; ++rt)
#pragma unroll
      for (int ct = 0; ct < 4; ++ct) {
        int coll = 64 * wc + 16 * ct + l15;
        float bb = b0[128 * h + coll];
#pragma unroll
        for (int r = 0; r < 4; ++r) {
          int rowl = 32 * wr + 16 * rt + 4 * g + r;
          float z = acc[rt][ct][r] + bb;
          z = (z > 0.f) ? z : 0.01f * z;
          __bf16 hv = (__bf16)z;
          unsigned bo = (unsigned)(rowl * 256 + coll * 2) ^ ((rowl & 7) << 4);
          *(__bf16*)((char*)HaS + bo) = hv;
          *(__bf16*)((char*)LaS + bo) = (__bf16)(z - (float)hv);
        }
      }
    __syncthreads();

    // ---- Phase B (half h): acc2 += ha_half @ W1t[:, 128h..128h+128) ----
    for (int ks = 0; ks < 4; ++ks) {
      int kl = ks * 32;
      bf16x8 ah2[2], al2[2], b2h[4], b2l[4];
#pragma unroll
      for (int rt = 0; rt < 2; ++rt) {
        int rowl = 32 * wr + 16 * rt + l15;
        unsigned bo = (unsigned)(rowl * 256 + (kl + lk) * 2) ^ ((rowl & 7) << 4);
        ah2[rt] = *(const bf16x8*)((char*)HaS + bo);
        al2[rt] = *(const bf16x8*)((char*)LaS + bo);
      }
#pragma unroll
      for (int ct = 0; ct < 4; ++ct) {
        size_t off = (size_t)((4 * wc + ct) * 8 + 4 * h + ks) * 512 + lane * 8;
        b2h[ct] = *(const bf16x8*)(w1h + off);
        b2l[ct] = *(const bf16x8*)(w1l + off);
      }
#pragma unroll
      for (int rt = 0; rt < 2; ++rt)
#pragma unroll
        for (int ct = 0; ct < 4; ++ct) {
          acc2[rt][ct] = __builtin_amdgcn_mfma_f32_16x16x32_bf16(ah2[rt], b2h[ct], acc2[rt][ct], 0, 0, 0);
          acc2[rt][ct] = __builtin_amdgcn_mfma_f32_16x16x32_bf16(al2[rt], b2h[ct], acc2[rt][ct], 0, 0, 0);
          acc2[rt][ct] = __builtin_amdgcn_mfma_f32_16x16x32_bf16(ah2[rt], b2l[ct], acc2[rt][ct], 0, 0, 0);
        }
    }
    __syncthreads();
  }

  // ---- final: bias1 + leaky, dot Wf, 16-lane reduce, cross-wave-col partials ----
  float* partS = (float*)HaS;
#pragma unroll
  for (int rt = 0; rt < 2; ++rt) {
#pragma unroll
    for (int r = 0; r < 4; ++r) {
      int rowl = 32 * wr + 16 * rt + 4 * g + r;
      float p = 0.f;
#pragma unroll
      for (int ct = 0; ct < 4; ++ct) {
        int c = 64 * wc + 16 * ct + l15;
        float z = acc2[rt][ct][r] + b1[c];
        z = (z > 0.f) ? z : 0.01f * z;
        p += z * Wf[c];
      }
      p += __shfl_xor(p, 1);
      p += __shfl_xor(p, 2);
      p += __shfl_xor(p, 4);
      p += __shfl_xor(p, 8);
      if (l15 == 0) partS[wc * 64 + rowl] = p;
    }
  }
  __syncthreads();
  if (t < 64) {
    int gl = bm0 + t;
    if (gl < N_NODES) {
      float z = partS[t] + partS[64 + t] + fbias[0];
      out[gl] = 1.0f / (1.0f + expf(-z));
    }
  }
}

extern "C" void kernel_launch(void* const* d_in, const int* in_sizes, int n_in,
                              void* d_out, int out_size, void* d_ws, size_t ws_size,
                              hipStream_t stream)
{
  const float* x     = (const float*)d_in[0];
  const int*   ei    = (const int*)d_in[1];
  const int*   batch = (const int*)d_in[2];
  const float* convW = (const float*)d_in[3];
  const float* convb = (const float*)d_in[4];
  const float* gam   = (const float*)d_in[5];
  const float* bet   = (const float*)d_in[6];
  const float* mean  = (const float*)d_in[7];
  const float* var   = (const float*)d_in[8];
  const float* eps   = (const float*)d_in[9];
  const float* W0    = (const float*)d_in[10];
  const float* b0    = (const float*)d_in[11];
  const float* W1    = (const float*)d_in[12];
  const float* b1    = (const float*)d_in[13];
  const float* Wf    = (const float*)d_in[14];
  const float* fb    = (const float*)d_in[15];
  float* out = (float*)d_out;

  // ---- workspace layout (float offsets), peak ~160.3 MB ----
  float* ws = (float*)d_ws;
  __bf16* A0hi = (__bf16*)(ws);
  __bf16* A0lo = (__bf16*)(ws + 12812288);
  float*  y    = ws + 25624576;
  __bf16* xhi  = (__bf16*)(ws + 32030720);
  __bf16* xlo  = (__bf16*)(ws + 35230720);
  int* deg     = (int*)(ws + 38436864);
  int* incl    = (int*)(ws + 38536864);
  int* row_ptr = (int*)(ws + 38636864);
  int* cursor  = (int*)(ws + 38736896);
  int* srcs    = (int*)(ws + 38836896);
  int* bsum    = (int*)(ws + 39836896);
  float* hpool = ws + 39836960;
  __bf16* w0hi = (__bf16*)(ws + 39964960);
  __bf16* w0lo = (__bf16*)(ws + 39997728);
  __bf16* w1hi = (__bf16*)(ws + 40030496);
  __bf16* w1lo = (__bf16*)(ws + 40046880);
  __bf16* cwhi = (__bf16*)(ws + 40063264);
  __bf16* cwlo = (__bf16*)(ws + 40069408);

  dim3 b256(256);

  wconv_kernel<<<256, b256, 0, stream>>>(W0, W1, convW, w0hi, w0lo, w1hi, w1lo, cwhi, cwlo);

  // ---- CSR build (once) ----
  hipMemsetAsync(deg, 0, (size_t)N_NODES * sizeof(int), stream);
  deg_hist_kernel<<<(N_EDGES + 255) / 256, b256, 0, stream>>>(ei, deg);
  scan1_kernel<<<(N_NODES + 2047) / 2048, b256, 0, stream>>>(deg, incl, bsum);
  scan2_kernel<<<1, 64, 0, stream>>>(bsum, (N_NODES + 2047) / 2048);
  scan3_kernel<<<(N_NODES + 255) / 256, b256, 0, stream>>>(incl, bsum, deg, row_ptr, cursor);
  fill_csr_kernel<<<(N_EDGES + 255) / 256, b256, 0, stream>>>(ei, cursor, srcs);

  hipMemsetAsync(hpool, 0, (size_t)N_GRAPHS * D * sizeof(float), stream);
  split_x_kernel<<<(N_NODES * 16 + 255) / 256, b256, 0, stream>>>(x, xhi, xlo);

  int ygrid = PADM / 64;                       // 1564
  int aggGrid = (N_NODES * 64 + 255) / 256;    // 25000: one wave per node

  // layer 0: x packed (FPR=2), out cols 0..63
  ygemm_kernel<<<ygrid, b256, 0, stream>>>(xhi, xlo, 2, 0, cwhi, cwlo, y);
  agg_bn_kernel<0><<<aggGrid, b256, 0, stream>>>(
      y, row_ptr, srcs, convb, gam, bet, mean, var, eps, A0hi, A0lo, 0, nullptr, nullptr);
  // layer 1: A0 cols 0..63 (FPR=8, fbase=0), out cols 64..127
  ygemm_kernel<<<ygrid, b256, 0, stream>>>(A0hi, A0lo, 8, 0, cwhi + 4096, cwlo + 4096, y);
  agg_bn_kernel<0><<<aggGrid, b256, 0, stream>>>(
      y, row_ptr, srcs, convb + D, gam + D, bet + D, mean + D, var + D, eps + 1,
      A0hi, A0lo, 64, nullptr, nullptr);
  // layer 2: A0 cols 64..127 (fbase=2), out cols 128..191 + pool
  ygemm_kernel<<<ygrid, b256, 0, stream>>>(A0hi, A0lo, 8, 2, cwhi + 8192, cwlo + 8192, y);
  agg_bn_kernel<1><<<aggGrid, b256, 0, stream>>>(
      y, row_ptr, srcs, convb + 2 * D, gam + 2 * D, bet + 2 * D, mean + 2 * D,
      var + 2 * D, eps + 2, A0hi, A0lo, 128, hpool, batch);

  pool_expand_kernel<<<(N_NODES * 16 + 255) / 256, b256, 0, stream>>>(hpool, batch, A0hi, A0lo);

  // ---- fused classifier: 64 rows/block, 256 threads, packed operand loads ----
  clf_fused_kernel<<<PADM / 64, b256, 0, stream>>>(
      A0hi, A0lo, w0hi, w0lo, b0, w1hi, w1lo, b1, Wf, fb, out);
}